// Round 10
// baseline (392.866 us; speedup 1.0000x reference)
//
#include <hip/hip_runtime.h>
#include <hip/hip_bf16.h>
#include <math.h>

// Problem constants
#define BB 2
#define SS 2048
#define DD 1024
#define HH 16
#define DHH 64
#define MM (BB * SS) // 4096

typedef float f32x4 __attribute__((ext_vector_type(4)));
typedef __bf16 bf16x8 __attribute__((ext_vector_type(8)));

#define N_QKV ((size_t)MM * DD)
#define N_W   ((size_t)DD * DD)

// ---- fallback scratch (used only if ws_size is too small) -----------------
__device__ unsigned short g_X [3][N_QKV];   // bf16 activations
__device__ unsigned short g_Q [N_QKV];      // bf16 Q*0.125  [m][n]
__device__ unsigned short g_K [N_QKV];      // bf16 K        [m][n]
__device__ unsigned short g_Vt[N_QKV];      // bf16 V^T [b][h][dh][s]
__device__ unsigned short g_Wt[3][N_W];     // bf16 Wt[n][k]

// fp32 -> bf16 RNE
__device__ __forceinline__ unsigned short f2bu(float f) {
    unsigned u = __float_as_uint(f);
    unsigned r = u + 0x7FFFu + ((u >> 16) & 1u);
    return (unsigned short)(r >> 16);
}

union FragU { uint4 u; bf16x8 v; unsigned short s[8]; };
static __device__ __forceinline__ bf16x8 ldfrag(const unsigned short* p) {
    FragU f; f.u = *(const uint4*)p; return f.v;
}

// ---------------------------------------------------------------------------
// Activations fp32 -> bf16, merged. Grid (4096, 3).
__global__ __launch_bounds__(256) void cvt3(
        const float* __restrict__ x0, const float* __restrict__ x1,
        const float* __restrict__ x2, unsigned short* __restrict__ X)
{
    const float* src = blockIdx.y == 0 ? x0 : (blockIdx.y == 1 ? x1 : x2);
    unsigned short* dst = X + (size_t)blockIdx.y * N_QKV;
    const size_t i = ((size_t)blockIdx.x * 256 + threadIdx.x) * 4;
    const float4 v = *(const float4*)(src + i);
    ushort4 s;
    s.x = f2bu(v.x); s.y = f2bu(v.y); s.z = f2bu(v.z); s.w = f2bu(v.w);
    *(ushort4*)(dst + i) = s;
}

// ---------------------------------------------------------------------------
// Wt[n][k] = bf16(W[k][n]), merged. Grid (16,16,3).
__global__ __launch_bounds__(256) void transpose_w3(
        const float* __restrict__ W0, const float* __restrict__ W1,
        const float* __restrict__ W2, unsigned short* __restrict__ Wt3)
{
    const float* W = blockIdx.z == 0 ? W0 : (blockIdx.z == 1 ? W1 : W2);
    unsigned short* Wt = Wt3 + (size_t)blockIdx.z * N_W;
    __shared__ float Ts[64][65];
    const int t = threadIdx.x;
    const int k0 = blockIdx.y * 64, n0 = blockIdx.x * 64;
#pragma unroll
    for (int i = 0; i < 16; ++i) {
        const int f = t + 256 * i, r = f >> 6, c = f & 63;
        Ts[r][c] = W[(size_t)(k0 + r) * DD + n0 + c];
    }
    __syncthreads();
#pragma unroll
    for (int i = 0; i < 16; ++i) {
        const int f = t + 256 * i, r = f >> 6, c = f & 63;
        Wt[(size_t)(n0 + r) * DD + k0 + c] = f2bu(Ts[c][r]);
    }
}

// ---------------------------------------------------------------------------
// Merged projection GEMM with register prefetch: z=0 Q (scale 1/8), z=1 K,
// z=2 V^T. bf16 x bf16, 128x128 tile, BK=64, 4 waves 2x2. Grid (8, 32, 3).
__global__ __launch_bounds__(256) void proj3(
        const unsigned short* __restrict__ X, const unsigned short* __restrict__ Wt3,
        const float* __restrict__ bq, const float* __restrict__ bk,
        const float* __restrict__ bv,
        unsigned short* __restrict__ Qp, unsigned short* __restrict__ Kp,
        unsigned short* __restrict__ Vtp)
{
    const int z = blockIdx.z;
    const unsigned short* xb = X   + (size_t)z * N_QKV;
    const unsigned short* Wt = Wt3 + (size_t)z * N_W;
    const float* bias = z == 0 ? bq : (z == 1 ? bk : bv);
    const float scale = z == 0 ? 0.125f : 1.0f;

    __shared__ unsigned short As[128][72];
    __shared__ unsigned short Bs[128][72];
    const int t = threadIdx.x, lane = t & 63, w = t >> 6;
    const int q = lane >> 4, li = lane & 15;
    const int wm = (w >> 1) * 64, wn = (w & 1) * 64;
    const int m0 = blockIdx.y * 128, n0 = blockIdx.x * 128;

    f32x4 acc[4][4];
#pragma unroll
    for (int mt = 0; mt < 4; ++mt)
#pragma unroll
        for (int nt = 0; nt < 4; ++nt) acc[mt][nt] = (f32x4)0.f;

    uint4 pa[4], pb[4];
    auto LD = [&](int kk) {
#pragma unroll
        for (int i = 0; i < 4; ++i) {
            const int f = t + 256 * i, r = f >> 3, c = (f & 7) * 8;
            pa[i] = *(const uint4*)(xb + (size_t)(m0 + r) * DD + kk + c);
            pb[i] = *(const uint4*)(Wt + (size_t)(n0 + r) * DD + kk + c);
        }
    };
    LD(0);

    for (int kk = 0; kk < DD; kk += 64) {
#pragma unroll
        for (int i = 0; i < 4; ++i) {
            const int f = t + 256 * i, r = f >> 3, c = (f & 7) * 8;
            *(uint4*)&As[r][c] = pa[i];
            *(uint4*)&Bs[r][c] = pb[i];
        }
        __syncthreads();                       // tile visible
        if (kk + 64 < DD) LD(kk + 64);         // prefetch overlaps MFMA phase
#pragma unroll
        for (int ks = 0; ks < 64; ks += 32) {
            bf16x8 a[4], b[4];
#pragma unroll
            for (int mt = 0; mt < 4; ++mt) a[mt] = ldfrag(&As[wm + mt * 16 + li][ks + q * 8]);
#pragma unroll
            for (int nt = 0; nt < 4; ++nt) b[nt] = ldfrag(&Bs[wn + nt * 16 + li][ks + q * 8]);
#pragma unroll
            for (int mt = 0; mt < 4; ++mt)
#pragma unroll
                for (int nt = 0; nt < 4; ++nt)
                    acc[mt][nt] = __builtin_amdgcn_mfma_f32_16x16x32_bf16(
                        a[mt], b[nt], acc[mt][nt], 0, 0, 0);
        }
        __syncthreads();                       // reads done before overwrite
    }

    float bvv[4];
#pragma unroll
    for (int nt = 0; nt < 4; ++nt) bvv[nt] = bias[n0 + wn + nt * 16 + li];

    if (z < 2) {
        unsigned short* out = z == 0 ? Qp : Kp;
#pragma unroll
        for (int mt = 0; mt < 4; ++mt)
#pragma unroll
            for (int nt = 0; nt < 4; ++nt)
#pragma unroll
                for (int reg = 0; reg < 4; ++reg) {
                    const int m = m0 + wm + mt * 16 + q * 4 + reg;
                    out[(size_t)m * DD + n0 + wn + nt * 16 + li] =
                        f2bu((acc[mt][nt][reg] + bvv[nt]) * scale);
                }
    } else {
        const int b = m0 >> 11;          // 128-row m-tiles never cross batch
        const int h = (n0 + wn) >> 6;    // 64-wide wave n-slice == one head
#pragma unroll
        for (int mt = 0; mt < 4; ++mt)
#pragma unroll
            for (int nt = 0; nt < 4; ++nt) {
                const int s = (m0 & (SS - 1)) + wm + mt * 16 + q * 4;
                const int dh = nt * 16 + li;
                ushort4 sv;
                sv.x = f2bu(acc[mt][nt][0] + bvv[nt]);
                sv.y = f2bu(acc[mt][nt][1] + bvv[nt]);
                sv.z = f2bu(acc[mt][nt][2] + bvv[nt]);
                sv.w = f2bu(acc[mt][nt][3] + bvv[nt]);
                *(ushort4*)(Vtp + ((size_t)((b * HH + h) * DHH + dh)) * SS + s) = sv;
            }
    }
}

// ---------------------------------------------------------------------------
// MFMA flash attention, no-max softmax, l via all-ones MFMA, register
// prefetch of K/V, 2 barriers per K-tile (Psb is wave-private: same-wave
// LDS ops execute in order; compiler inserts the lgkm wait). Grid (32,16,2).
__global__ __launch_bounds__(256) void attn3(
        const unsigned short* __restrict__ Qg, const unsigned short* __restrict__ Kg,
        const unsigned short* __restrict__ Vtg,
        const float* __restrict__ queries, float* __restrict__ outp)
{
    __shared__ unsigned short Qs [64][72];
    __shared__ unsigned short Ks [64][72];
    __shared__ unsigned short Vts[64][72];
    __shared__ unsigned short Psb[64][72];   // bf16 P, wave-private rows

    const int t = threadIdx.x, lane = t & 63, w = t >> 6;
    const int q = lane >> 4, li = lane & 15;
    const int qt = blockIdx.x, h = blockIdx.y, b = blockIdx.z;

    // stage Q tile (pre-scaled by 1/8 in proj)
#pragma unroll
    for (int i = 0; i < 2; ++i) {
        const int f = t + 256 * i, r = f >> 3, c = (f & 7) * 8;
        *(uint4*)&Qs[r][c] =
            *(const uint4*)(Qg + (size_t)(b * SS + qt * 64 + r) * DD + h * DHH + c);
    }

    uint4 pk[2], pv[2];
    auto LDKV = [&](int s0) {
#pragma unroll
        for (int i = 0; i < 2; ++i) {
            const int f = t + 256 * i, r = f >> 3, c = (f & 7) * 8;
            pk[i] = *(const uint4*)(Kg + (size_t)(b * SS + s0 + r) * DD + h * DHH + c);
            pv[i] = *(const uint4*)(Vtg + ((size_t)((b * HH + h) * DHH + r)) * SS + s0 + c);
        }
    };
    LDKV(0);

    FragU ones;
#pragma unroll
    for (int j = 0; j < 8; ++j) ones.s[j] = 0x3F80;  // bf16 1.0

    f32x4 o[4], lacc;
#pragma unroll
    for (int nt = 0; nt < 4; ++nt) o[nt] = (f32x4)0.f;
    lacc = (f32x4)0.f;

    for (int kt = 0; kt < SS / 64; ++kt) {
        // publish staged K/V tile
#pragma unroll
        for (int i = 0; i < 2; ++i) {
            const int f = t + 256 * i, r = f >> 3, c = (f & 7) * 8;
            *(uint4*)&Ks[r][c]  = pk[i];
            *(uint4*)&Vts[r][c] = pv[i];
        }
        __syncthreads();                         // tile (and Qs) visible
        if (kt + 1 < SS / 64) LDKV((kt + 1) * 64);  // prefetch next tile

        // S = (Q/8) K^T
        f32x4 sc[4];
#pragma unroll
        for (int nt = 0; nt < 4; ++nt) sc[nt] = (f32x4)0.f;
#pragma unroll
        for (int ks = 0; ks < 64; ks += 32) {
            const bf16x8 a = ldfrag(&Qs[w * 16 + li][ks + q * 8]);
#pragma unroll
            for (int nt = 0; nt < 4; ++nt) {
                const bf16x8 bb = ldfrag(&Ks[nt * 16 + li][ks + q * 8]);
                sc[nt] = __builtin_amdgcn_mfma_f32_16x16x32_bf16(a, bb, sc[nt], 0, 0, 0);
            }
        }

        // P = exp(S) -> bf16 LDS (wave-private rows; no barrier needed)
#pragma unroll
        for (int nt = 0; nt < 4; ++nt)
#pragma unroll
            for (int reg = 0; reg < 4; ++reg)
                Psb[w * 16 + q * 4 + reg][nt * 16 + li] = f2bu(__expf(sc[nt][reg]));

        // O += P V ; l += P * 1
#pragma unroll
        for (int ks = 0; ks < 64; ks += 32) {
            const bf16x8 Pa = ldfrag(&Psb[w * 16 + li][ks + q * 8]);
#pragma unroll
            for (int nt = 0; nt < 4; ++nt) {
                const bf16x8 vb = ldfrag(&Vts[nt * 16 + li][ks + q * 8]);
                o[nt] = __builtin_amdgcn_mfma_f32_16x16x32_bf16(Pa, vb, o[nt], 0, 0, 0);
            }
            lacc = __builtin_amdgcn_mfma_f32_16x16x32_bf16(Pa, ones.v, lacc, 0, 0, 0);
        }
        __syncthreads();  // all reads done before next publish
    }

    float inv[4];
#pragma unroll
    for (int reg = 0; reg < 4; ++reg) inv[reg] = 1.f / lacc[reg];
#pragma unroll
    for (int nt = 0; nt < 4; ++nt)
#pragma unroll
        for (int reg = 0; reg < 4; ++reg) {
            const size_t g = (size_t)(b * SS + qt * 64 + w * 16 + q * 4 + reg) * DD
                           + h * DHH + nt * 16 + li;
            outp[g] = o[nt][reg] * inv[reg] + queries[g];
        }
}

// ---------------------------------------------------------------------------
extern "C" void kernel_launch(void* const* d_in, const int* in_sizes, int n_in,
                              void* d_out, int out_size, void* d_ws, size_t ws_size,
                              hipStream_t stream) {
    const float* queries = (const float*)d_in[0];
    const float* keys    = (const float*)d_in[1];
    const float* values  = (const float*)d_in[2];
    const float* Wq      = (const float*)d_in[3];
    const float* bq      = (const float*)d_in[4];
    const float* Wk      = (const float*)d_in[5];
    const float* bk      = (const float*)d_in[6];
    const float* Wv      = (const float*)d_in[7];
    const float* bv      = (const float*)d_in[8];
    float* outp = (float*)d_out;

    // scratch: prefer d_ws (54 MB needed); fall back to device globals.
    const size_t need = (6 * N_QKV + 3 * N_W) * sizeof(unsigned short);
    unsigned short *Xp, *Qp, *Kp, *Vtp, *Wtp;
    if (ws_size >= need) {
        Xp  = (unsigned short*)d_ws;
        Qp  = Xp + 3 * N_QKV;
        Kp  = Qp + N_QKV;
        Vtp = Kp + N_QKV;
        Wtp = Vtp + N_QKV;
    } else {
        hipGetSymbolAddress((void**)&Xp,  HIP_SYMBOL(g_X));
        hipGetSymbolAddress((void**)&Qp,  HIP_SYMBOL(g_Q));
        hipGetSymbolAddress((void**)&Kp,  HIP_SYMBOL(g_K));
        hipGetSymbolAddress((void**)&Vtp, HIP_SYMBOL(g_Vt));
        hipGetSymbolAddress((void**)&Wtp, HIP_SYMBOL(g_Wt));
    }

    const dim3 bp(256);
    cvt3<<<dim3(MM * DD / 1024, 3), bp, 0, stream>>>(queries, keys, values, Xp);
    transpose_w3<<<dim3(16, 16, 3), bp, 0, stream>>>(Wq, Wk, Wv, Wtp);
    proj3<<<dim3(8, 32, 3), bp, 0, stream>>>(Xp, Wtp, bq, bk, bv, Qp, Kp, Vtp);
    attn3<<<dim3(SS / 64, HH, BB), bp, 0, stream>>>(Qp, Kp, Vtp, queries, outp);
}

// Round 11
// 225.450 us; speedup vs baseline: 1.7426x; 1.7426x over previous
//
#include <hip/hip_runtime.h>
#include <hip/hip_bf16.h>
#include <math.h>

// Problem constants
#define BB 2
#define SS 2048
#define DD 1024
#define HH 16
#define DHH 64
#define MM (BB * SS) // 4096

typedef float f32x4 __attribute__((ext_vector_type(4)));
typedef __bf16 bf16x8 __attribute__((ext_vector_type(8)));

#define N_QKV ((size_t)MM * DD)
#define N_W   ((size_t)DD * DD)

// ---- fallback scratch (used only if ws_size is too small) -----------------
__device__ unsigned short g_X [3][N_QKV];   // bf16 activations
__device__ unsigned short g_Q [N_QKV];      // bf16 Q*0.125  [m][n]
__device__ unsigned short g_K [N_QKV];      // bf16 K        [m][n]
__device__ unsigned short g_Vt[N_QKV];      // bf16 V^T [b][h][dh][s]
__device__ unsigned short g_Wt[3][N_W];     // bf16 Wt[n][k]

// fp32 -> bf16 RNE
__device__ __forceinline__ unsigned short f2bu(float f) {
    unsigned u = __float_as_uint(f);
    unsigned r = u + 0x7FFFu + ((u >> 16) & 1u);
    return (unsigned short)(r >> 16);
}

union FragU { uint4 u; bf16x8 v; unsigned short s[8]; };
static __device__ __forceinline__ bf16x8 ldfrag(const unsigned short* p) {
    FragU f; f.u = *(const uint4*)p; return f.v;
}

// ---------------------------------------------------------------------------
// Activations fp32 -> bf16, merged. Grid (4096, 3).
__global__ __launch_bounds__(256) void cvt3(
        const float* __restrict__ x0, const float* __restrict__ x1,
        const float* __restrict__ x2, unsigned short* __restrict__ X)
{
    const float* src = blockIdx.y == 0 ? x0 : (blockIdx.y == 1 ? x1 : x2);
    unsigned short* dst = X + (size_t)blockIdx.y * N_QKV;
    const size_t i = ((size_t)blockIdx.x * 256 + threadIdx.x) * 4;
    const float4 v = *(const float4*)(src + i);
    ushort4 s;
    s.x = f2bu(v.x); s.y = f2bu(v.y); s.z = f2bu(v.z); s.w = f2bu(v.w);
    *(ushort4*)(dst + i) = s;
}

// ---------------------------------------------------------------------------
// Wt[n][k] = bf16(W[k][n]), merged. Grid (16,16,3).
__global__ __launch_bounds__(256) void transpose_w3(
        const float* __restrict__ W0, const float* __restrict__ W1,
        const float* __restrict__ W2, unsigned short* __restrict__ Wt3)
{
    const float* W = blockIdx.z == 0 ? W0 : (blockIdx.z == 1 ? W1 : W2);
    unsigned short* Wt = Wt3 + (size_t)blockIdx.z * N_W;
    __shared__ float Ts[64][65];
    const int t = threadIdx.x;
    const int k0 = blockIdx.y * 64, n0 = blockIdx.x * 64;
#pragma unroll
    for (int i = 0; i < 16; ++i) {
        const int f = t + 256 * i, r = f >> 6, c = f & 63;
        Ts[r][c] = W[(size_t)(k0 + r) * DD + n0 + c];
    }
    __syncthreads();
#pragma unroll
    for (int i = 0; i < 16; ++i) {
        const int f = t + 256 * i, r = f >> 6, c = f & 63;
        Wt[(size_t)(n0 + r) * DD + k0 + c] = f2bu(Ts[c][r]);
    }
}

// ---------------------------------------------------------------------------
// Merged projection GEMM with scalar register prefetch: z=0 Q (scale 1/8),
// z=1 K, z=2 V^T. bf16 x bf16, 128x128 tile, BK=64, 4 waves 2x2. Grid (8,32,3).
// Prefetch regs are NAMED SCALARS (no arrays/lambdas -> no alloca/spill; R10's
// array+lambda version spilled 281 MB to scratch).
__global__ __launch_bounds__(256) void proj3(
        const unsigned short* __restrict__ X, const unsigned short* __restrict__ Wt3,
        const float* __restrict__ bq, const float* __restrict__ bk,
        const float* __restrict__ bv,
        unsigned short* __restrict__ Qp, unsigned short* __restrict__ Kp,
        unsigned short* __restrict__ Vtp)
{
    const int z = blockIdx.z;
    const unsigned short* xb = X   + (size_t)z * N_QKV;
    const unsigned short* Wt = Wt3 + (size_t)z * N_W;
    const float* bias = z == 0 ? bq : (z == 1 ? bk : bv);
    const float scale = z == 0 ? 0.125f : 1.0f;

    __shared__ unsigned short As[128][72];
    __shared__ unsigned short Bs[128][72];
    const int t = threadIdx.x, lane = t & 63, w = t >> 6;
    const int q = lane >> 4, li = lane & 15;
    const int wm = (w >> 1) * 64, wn = (w & 1) * 64;
    const int m0 = blockIdx.y * 128, n0 = blockIdx.x * 128;
    const int rs = t >> 3, cs = (t & 7) * 8;   // staging row/col

    f32x4 acc[4][4];
#pragma unroll
    for (int mt = 0; mt < 4; ++mt)
#pragma unroll
        for (int nt = 0; nt < 4; ++nt) acc[mt][nt] = (f32x4)0.f;

    uint4 pa0, pa1, pa2, pa3, pb0, pb1, pb2, pb3;
#define PROJ_LD(kk) \
    pa0 = *(const uint4*)(xb + (size_t)(m0 + rs      ) * DD + (kk) + cs); \
    pa1 = *(const uint4*)(xb + (size_t)(m0 + rs + 32 ) * DD + (kk) + cs); \
    pa2 = *(const uint4*)(xb + (size_t)(m0 + rs + 64 ) * DD + (kk) + cs); \
    pa3 = *(const uint4*)(xb + (size_t)(m0 + rs + 96 ) * DD + (kk) + cs); \
    pb0 = *(const uint4*)(Wt + (size_t)(n0 + rs      ) * DD + (kk) + cs); \
    pb1 = *(const uint4*)(Wt + (size_t)(n0 + rs + 32 ) * DD + (kk) + cs); \
    pb2 = *(const uint4*)(Wt + (size_t)(n0 + rs + 64 ) * DD + (kk) + cs); \
    pb3 = *(const uint4*)(Wt + (size_t)(n0 + rs + 96 ) * DD + (kk) + cs);

    PROJ_LD(0)

    for (int kk = 0; kk < DD; kk += 64) {
        *(uint4*)&As[rs     ][cs] = pa0;
        *(uint4*)&As[rs + 32][cs] = pa1;
        *(uint4*)&As[rs + 64][cs] = pa2;
        *(uint4*)&As[rs + 96][cs] = pa3;
        *(uint4*)&Bs[rs     ][cs] = pb0;
        *(uint4*)&Bs[rs + 32][cs] = pb1;
        *(uint4*)&Bs[rs + 64][cs] = pb2;
        *(uint4*)&Bs[rs + 96][cs] = pb3;
        __syncthreads();                       // tile visible
        if (kk + 64 < DD) { PROJ_LD(kk + 64) } // prefetch overlaps MFMA phase
#pragma unroll
        for (int ks = 0; ks < 64; ks += 32) {
            bf16x8 a[4], b[4];
#pragma unroll
            for (int mt = 0; mt < 4; ++mt) a[mt] = ldfrag(&As[wm + mt * 16 + li][ks + q * 8]);
#pragma unroll
            for (int nt = 0; nt < 4; ++nt) b[nt] = ldfrag(&Bs[wn + nt * 16 + li][ks + q * 8]);
#pragma unroll
            for (int mt = 0; mt < 4; ++mt)
#pragma unroll
                for (int nt = 0; nt < 4; ++nt)
                    acc[mt][nt] = __builtin_amdgcn_mfma_f32_16x16x32_bf16(
                        a[mt], b[nt], acc[mt][nt], 0, 0, 0);
        }
        __syncthreads();                       // reads done before overwrite
    }
#undef PROJ_LD

    float bvv[4];
#pragma unroll
    for (int nt = 0; nt < 4; ++nt) bvv[nt] = bias[n0 + wn + nt * 16 + li];

    if (z < 2) {
        unsigned short* out = z == 0 ? Qp : Kp;
#pragma unroll
        for (int mt = 0; mt < 4; ++mt)
#pragma unroll
            for (int nt = 0; nt < 4; ++nt)
#pragma unroll
                for (int reg = 0; reg < 4; ++reg) {
                    const int m = m0 + wm + mt * 16 + q * 4 + reg;
                    out[(size_t)m * DD + n0 + wn + nt * 16 + li] =
                        f2bu((acc[mt][nt][reg] + bvv[nt]) * scale);
                }
    } else {
        const int b = m0 >> 11;          // 128-row m-tiles never cross batch
        const int h = (n0 + wn) >> 6;    // 64-wide wave n-slice == one head
#pragma unroll
        for (int mt = 0; mt < 4; ++mt)
#pragma unroll
            for (int nt = 0; nt < 4; ++nt) {
                const int s = (m0 & (SS - 1)) + wm + mt * 16 + q * 4;
                const int dh = nt * 16 + li;
                ushort4 sv;
                sv.x = f2bu(acc[mt][nt][0] + bvv[nt]);
                sv.y = f2bu(acc[mt][nt][1] + bvv[nt]);
                sv.z = f2bu(acc[mt][nt][2] + bvv[nt]);
                sv.w = f2bu(acc[mt][nt][3] + bvv[nt]);
                *(ushort4*)(Vtp + ((size_t)((b * HH + h) * DHH + dh)) * SS + s) = sv;
            }
    }
}

// ---------------------------------------------------------------------------
// MFMA flash attention, no-max softmax, l via all-ones MFMA, scalar register
// prefetch of K/V, 2 barriers per K-tile. Grid (32,16,2).
__global__ __launch_bounds__(256) void attn3(
        const unsigned short* __restrict__ Qg, const unsigned short* __restrict__ Kg,
        const unsigned short* __restrict__ Vtg,
        const float* __restrict__ queries, float* __restrict__ outp)
{
    __shared__ unsigned short Qs [64][72];
    __shared__ unsigned short Ks [64][72];
    __shared__ unsigned short Vts[64][72];
    __shared__ unsigned short Psb[64][72];   // bf16 P, wave-private rows

    const int t = threadIdx.x, lane = t & 63, w = t >> 6;
    const int q = lane >> 4, li = lane & 15;
    const int qt = blockIdx.x, h = blockIdx.y, b = blockIdx.z;
    const int rs = t >> 3, cs = (t & 7) * 8;   // staging row/col

    // stage Q tile (pre-scaled by 1/8 in proj)
    *(uint4*)&Qs[rs     ][cs] =
        *(const uint4*)(Qg + (size_t)(b * SS + qt * 64 + rs) * DD + h * DHH + cs);
    *(uint4*)&Qs[rs + 32][cs] =
        *(const uint4*)(Qg + (size_t)(b * SS + qt * 64 + rs + 32) * DD + h * DHH + cs);

    uint4 pk0, pk1, pv0, pv1;
#define ATTN_LD(s0) \
    pk0 = *(const uint4*)(Kg  + (size_t)(b * SS + (s0) + rs) * DD + h * DHH + cs); \
    pk1 = *(const uint4*)(Kg  + (size_t)(b * SS + (s0) + rs + 32) * DD + h * DHH + cs); \
    pv0 = *(const uint4*)(Vtg + ((size_t)((b * HH + h) * DHH + rs)) * SS + (s0) + cs); \
    pv1 = *(const uint4*)(Vtg + ((size_t)((b * HH + h) * DHH + rs + 32)) * SS + (s0) + cs);

    ATTN_LD(0)

    FragU ones;
#pragma unroll
    for (int j = 0; j < 8; ++j) ones.s[j] = 0x3F80;  // bf16 1.0

    f32x4 o[4], lacc;
#pragma unroll
    for (int nt = 0; nt < 4; ++nt) o[nt] = (f32x4)0.f;
    lacc = (f32x4)0.f;

    for (int kt = 0; kt < SS / 64; ++kt) {
        // publish staged K/V tile
        *(uint4*)&Ks [rs     ][cs] = pk0;
        *(uint4*)&Ks [rs + 32][cs] = pk1;
        *(uint4*)&Vts[rs     ][cs] = pv0;
        *(uint4*)&Vts[rs + 32][cs] = pv1;
        __syncthreads();                         // tile (and Qs) visible
        if (kt + 1 < SS / 64) { ATTN_LD((kt + 1) * 64) }  // prefetch next tile

        // S = (Q/8) K^T
        f32x4 sc[4];
#pragma unroll
        for (int nt = 0; nt < 4; ++nt) sc[nt] = (f32x4)0.f;
#pragma unroll
        for (int ks = 0; ks < 64; ks += 32) {
            const bf16x8 a = ldfrag(&Qs[w * 16 + li][ks + q * 8]);
#pragma unroll
            for (int nt = 0; nt < 4; ++nt) {
                const bf16x8 bb = ldfrag(&Ks[nt * 16 + li][ks + q * 8]);
                sc[nt] = __builtin_amdgcn_mfma_f32_16x16x32_bf16(a, bb, sc[nt], 0, 0, 0);
            }
        }

        // P = exp(S) -> bf16 LDS (wave-private rows; same-wave order + lgkm wait)
#pragma unroll
        for (int nt = 0; nt < 4; ++nt)
#pragma unroll
            for (int reg = 0; reg < 4; ++reg)
                Psb[w * 16 + q * 4 + reg][nt * 16 + li] = f2bu(__expf(sc[nt][reg]));

        // O += P V ; l += P * 1
#pragma unroll
        for (int ks = 0; ks < 64; ks += 32) {
            const bf16x8 Pa = ldfrag(&Psb[w * 16 + li][ks + q * 8]);
#pragma unroll
            for (int nt = 0; nt < 4; ++nt) {
                const bf16x8 vb = ldfrag(&Vts[nt * 16 + li][ks + q * 8]);
                o[nt] = __builtin_amdgcn_mfma_f32_16x16x32_bf16(Pa, vb, o[nt], 0, 0, 0);
            }
            lacc = __builtin_amdgcn_mfma_f32_16x16x32_bf16(Pa, ones.v, lacc, 0, 0, 0);
        }
        __syncthreads();  // all reads done before next publish
    }
#undef ATTN_LD

    float inv[4];
#pragma unroll
    for (int reg = 0; reg < 4; ++reg) inv[reg] = 1.f / lacc[reg];
#pragma unroll
    for (int nt = 0; nt < 4; ++nt)
#pragma unroll
        for (int reg = 0; reg < 4; ++reg) {
            const size_t g = (size_t)(b * SS + qt * 64 + w * 16 + q * 4 + reg) * DD
                           + h * DHH + nt * 16 + li;
            outp[g] = o[nt][reg] * inv[reg] + queries[g];
        }
}

// ---------------------------------------------------------------------------
extern "C" void kernel_launch(void* const* d_in, const int* in_sizes, int n_in,
                              void* d_out, int out_size, void* d_ws, size_t ws_size,
                              hipStream_t stream) {
    const float* queries = (const float*)d_in[0];
    const float* keys    = (const float*)d_in[1];
    const float* values  = (const float*)d_in[2];
    const float* Wq      = (const float*)d_in[3];
    const float* bq      = (const float*)d_in[4];
    const float* Wk      = (const float*)d_in[5];
    const float* bk      = (const float*)d_in[6];
    const float* Wv      = (const float*)d_in[7];
    const float* bv      = (const float*)d_in[8];
    float* outp = (float*)d_out;

    // scratch: prefer d_ws (54 MB needed); fall back to device globals.
    const size_t need = (6 * N_QKV + 3 * N_W) * sizeof(unsigned short);
    unsigned short *Xp, *Qp, *Kp, *Vtp, *Wtp;
    if (ws_size >= need) {
        Xp  = (unsigned short*)d_ws;
        Qp  = Xp + 3 * N_QKV;
        Kp  = Qp + N_QKV;
        Vtp = Kp + N_QKV;
        Wtp = Vtp + N_QKV;
    } else {
        hipGetSymbolAddress((void**)&Xp,  HIP_SYMBOL(g_X));
        hipGetSymbolAddress((void**)&Qp,  HIP_SYMBOL(g_Q));
        hipGetSymbolAddress((void**)&Kp,  HIP_SYMBOL(g_K));
        hipGetSymbolAddress((void**)&Vtp, HIP_SYMBOL(g_Vt));
        hipGetSymbolAddress((void**)&Wtp, HIP_SYMBOL(g_Wt));
    }

    const dim3 bp(256);
    cvt3<<<dim3(MM * DD / 1024, 3), bp, 0, stream>>>(queries, keys, values, Xp);
    transpose_w3<<<dim3(16, 16, 3), bp, 0, stream>>>(Wq, Wk, Wv, Wtp);
    proj3<<<dim3(8, 32, 3), bp, 0, stream>>>(Xp, Wtp, bq, bk, bv, Qp, Kp, Vtp);
    attn3<<<dim3(SS / 64, HH, BB), bp, 0, stream>>>(Qp, Kp, Vtp, queries, outp);
}

// Round 12
// 213.629 us; speedup vs baseline: 1.8390x; 1.0553x over previous
//
#include <hip/hip_runtime.h>
#include <hip/hip_bf16.h>
#include <math.h>

// Problem constants
#define BB 2
#define SS 2048
#define DD 1024
#define HH 16
#define DHH 64
#define MM (BB * SS) // 4096

typedef float f32x4 __attribute__((ext_vector_type(4)));
typedef __bf16 bf16x8 __attribute__((ext_vector_type(8)));

#define N_QKV ((size_t)MM * DD)
#define N_W   ((size_t)DD * DD)

// ---- fallback scratch (used only if ws_size is too small) -----------------
__device__ unsigned short g_X [3][N_QKV];   // bf16 activations
__device__ unsigned short g_Q [N_QKV];      // bf16 Q*0.125  [m][n]
__device__ unsigned short g_K [N_QKV];      // bf16 K        [m][n]
__device__ unsigned short g_Vt[N_QKV];      // bf16 V^T [b][h][dh][s]
__device__ unsigned short g_Wt[3][N_W];     // bf16 Wt[n][k]

// fp32 -> bf16 RNE
__device__ __forceinline__ unsigned short f2bu(float f) {
    unsigned u = __float_as_uint(f);
    unsigned r = u + 0x7FFFu + ((u >> 16) & 1u);
    return (unsigned short)(r >> 16);
}

union FragU { uint4 u; bf16x8 v; unsigned short s[8]; };
static __device__ __forceinline__ bf16x8 ldfrag(const unsigned short* p) {
    FragU f; f.u = *(const uint4*)p; return f.v;
}

// ---------------------------------------------------------------------------
// Activations fp32 -> bf16, merged. Grid (4096, 3).
__global__ __launch_bounds__(256) void cvt3(
        const float* __restrict__ x0, const float* __restrict__ x1,
        const float* __restrict__ x2, unsigned short* __restrict__ X)
{
    const float* src = blockIdx.y == 0 ? x0 : (blockIdx.y == 1 ? x1 : x2);
    unsigned short* dst = X + (size_t)blockIdx.y * N_QKV;
    const size_t i = ((size_t)blockIdx.x * 256 + threadIdx.x) * 4;
    const float4 v = *(const float4*)(src + i);
    ushort4 s;
    s.x = f2bu(v.x); s.y = f2bu(v.y); s.z = f2bu(v.z); s.w = f2bu(v.w);
    *(ushort4*)(dst + i) = s;
}

// ---------------------------------------------------------------------------
// Wt[n][k] = bf16(W[k][n]), merged. Grid (16,16,3).
__global__ __launch_bounds__(256) void transpose_w3(
        const float* __restrict__ W0, const float* __restrict__ W1,
        const float* __restrict__ W2, unsigned short* __restrict__ Wt3)
{
    const float* W = blockIdx.z == 0 ? W0 : (blockIdx.z == 1 ? W1 : W2);
    unsigned short* Wt = Wt3 + (size_t)blockIdx.z * N_W;
    __shared__ float Ts[64][65];
    const int t = threadIdx.x;
    const int k0 = blockIdx.y * 64, n0 = blockIdx.x * 64;
#pragma unroll
    for (int i = 0; i < 16; ++i) {
        const int f = t + 256 * i, r = f >> 6, c = f & 63;
        Ts[r][c] = W[(size_t)(k0 + r) * DD + n0 + c];
    }
    __syncthreads();
#pragma unroll
    for (int i = 0; i < 16; ++i) {
        const int f = t + 256 * i, r = f >> 6, c = f & 63;
        Wt[(size_t)(n0 + r) * DD + k0 + c] = f2bu(Ts[c][r]);
    }
}

// ---------------------------------------------------------------------------
// Merged projection GEMM (unchanged from R11): z=0 Q (scale 1/8), z=1 K,
// z=2 V^T. 128x128 tile, BK=64, scalar-register prefetch. Grid (8,32,3).
__global__ __launch_bounds__(256) void proj3(
        const unsigned short* __restrict__ X, const unsigned short* __restrict__ Wt3,
        const float* __restrict__ bq, const float* __restrict__ bk,
        const float* __restrict__ bv,
        unsigned short* __restrict__ Qp, unsigned short* __restrict__ Kp,
        unsigned short* __restrict__ Vtp)
{
    const int z = blockIdx.z;
    const unsigned short* xb = X   + (size_t)z * N_QKV;
    const unsigned short* Wt = Wt3 + (size_t)z * N_W;
    const float* bias = z == 0 ? bq : (z == 1 ? bk : bv);
    const float scale = z == 0 ? 0.125f : 1.0f;

    __shared__ unsigned short As[128][72];
    __shared__ unsigned short Bs[128][72];
    const int t = threadIdx.x, lane = t & 63, w = t >> 6;
    const int q = lane >> 4, li = lane & 15;
    const int wm = (w >> 1) * 64, wn = (w & 1) * 64;
    const int m0 = blockIdx.y * 128, n0 = blockIdx.x * 128;
    const int rs = t >> 3, cs = (t & 7) * 8;   // staging row/col

    f32x4 acc[4][4];
#pragma unroll
    for (int mt = 0; mt < 4; ++mt)
#pragma unroll
        for (int nt = 0; nt < 4; ++nt) acc[mt][nt] = (f32x4)0.f;

    uint4 pa0, pa1, pa2, pa3, pb0, pb1, pb2, pb3;
#define PROJ_LD(kk) \
    pa0 = *(const uint4*)(xb + (size_t)(m0 + rs      ) * DD + (kk) + cs); \
    pa1 = *(const uint4*)(xb + (size_t)(m0 + rs + 32 ) * DD + (kk) + cs); \
    pa2 = *(const uint4*)(xb + (size_t)(m0 + rs + 64 ) * DD + (kk) + cs); \
    pa3 = *(const uint4*)(xb + (size_t)(m0 + rs + 96 ) * DD + (kk) + cs); \
    pb0 = *(const uint4*)(Wt + (size_t)(n0 + rs      ) * DD + (kk) + cs); \
    pb1 = *(const uint4*)(Wt + (size_t)(n0 + rs + 32 ) * DD + (kk) + cs); \
    pb2 = *(const uint4*)(Wt + (size_t)(n0 + rs + 64 ) * DD + (kk) + cs); \
    pb3 = *(const uint4*)(Wt + (size_t)(n0 + rs + 96 ) * DD + (kk) + cs);

    PROJ_LD(0)

    for (int kk = 0; kk < DD; kk += 64) {
        *(uint4*)&As[rs     ][cs] = pa0;
        *(uint4*)&As[rs + 32][cs] = pa1;
        *(uint4*)&As[rs + 64][cs] = pa2;
        *(uint4*)&As[rs + 96][cs] = pa3;
        *(uint4*)&Bs[rs     ][cs] = pb0;
        *(uint4*)&Bs[rs + 32][cs] = pb1;
        *(uint4*)&Bs[rs + 64][cs] = pb2;
        *(uint4*)&Bs[rs + 96][cs] = pb3;
        __syncthreads();                       // tile visible
        if (kk + 64 < DD) { PROJ_LD(kk + 64) } // prefetch overlaps MFMA phase
#pragma unroll
        for (int ks = 0; ks < 64; ks += 32) {
            bf16x8 a[4], b[4];
#pragma unroll
            for (int mt = 0; mt < 4; ++mt) a[mt] = ldfrag(&As[wm + mt * 16 + li][ks + q * 8]);
#pragma unroll
            for (int nt = 0; nt < 4; ++nt) b[nt] = ldfrag(&Bs[wn + nt * 16 + li][ks + q * 8]);
#pragma unroll
            for (int mt = 0; mt < 4; ++mt)
#pragma unroll
                for (int nt = 0; nt < 4; ++nt)
                    acc[mt][nt] = __builtin_amdgcn_mfma_f32_16x16x32_bf16(
                        a[mt], b[nt], acc[mt][nt], 0, 0, 0);
        }
        __syncthreads();                       // reads done before overwrite
    }
#undef PROJ_LD

    float bvv[4];
#pragma unroll
    for (int nt = 0; nt < 4; ++nt) bvv[nt] = bias[n0 + wn + nt * 16 + li];

    if (z < 2) {
        unsigned short* out = z == 0 ? Qp : Kp;
#pragma unroll
        for (int mt = 0; mt < 4; ++mt)
#pragma unroll
            for (int nt = 0; nt < 4; ++nt)
#pragma unroll
                for (int reg = 0; reg < 4; ++reg) {
                    const int m = m0 + wm + mt * 16 + q * 4 + reg;
                    out[(size_t)m * DD + n0 + wn + nt * 16 + li] =
                        f2bu((acc[mt][nt][reg] + bvv[nt]) * scale);
                }
    } else {
        const int b = m0 >> 11;          // 128-row m-tiles never cross batch
        const int h = (n0 + wn) >> 6;    // 64-wide wave n-slice == one head
#pragma unroll
        for (int mt = 0; mt < 4; ++mt)
#pragma unroll
            for (int nt = 0; nt < 4; ++nt) {
                const int s = (m0 & (SS - 1)) + wm + mt * 16 + q * 4;
                const int dh = nt * 16 + li;
                ushort4 sv;
                sv.x = f2bu(acc[mt][nt][0] + bvv[nt]);
                sv.y = f2bu(acc[mt][nt][1] + bvv[nt]);
                sv.z = f2bu(acc[mt][nt][2] + bvv[nt]);
                sv.w = f2bu(acc[mt][nt][3] + bvv[nt]);
                *(ushort4*)(Vtp + ((size_t)((b * HH + h) * DHH + dh)) * SS + s) = sv;
            }
    }
}

// ---------------------------------------------------------------------------
// attn4: 128 Q-rows per block, wave owns 32 rows (mt=2). K/V fragments reused
// across both mt sub-tiles -> b128 LDS reads per unit work halved (attn3 was
// LDS-pipe-bound ~95%). Q-frags hoisted to regs; Psb aliases the dead Qs LDS
// (both wave-private rows). No-max softmax; l via all-ones MFMA. Grid (16,16,2).
__global__ __launch_bounds__(256) void attn4(
        const unsigned short* __restrict__ Qg, const unsigned short* __restrict__ Kg,
        const unsigned short* __restrict__ Vtg,
        const float* __restrict__ queries, float* __restrict__ outp)
{
    __shared__ unsigned short QP [128][72];  // Q tile, then P (wave-private rows)
    __shared__ unsigned short Ks [64][72];
    __shared__ unsigned short Vts[64][72];

    const int t = threadIdx.x, lane = t & 63, w = t >> 6;
    const int q = lane >> 4, li = lane & 15;
    const int qt = blockIdx.x, h = blockIdx.y, b = blockIdx.z;
    const int rs = t >> 3, cs = (t & 7) * 8;   // staging row/col

    // stage Q tile (128x64, pre-scaled by 1/8 in proj)
    {
        const unsigned short* qsrc = Qg + (size_t)(b * SS + qt * 128) * DD + h * DHH + cs;
        *(uint4*)&QP[rs      ][cs] = *(const uint4*)(qsrc + (size_t)(rs      ) * DD);
        *(uint4*)&QP[rs + 32 ][cs] = *(const uint4*)(qsrc + (size_t)(rs + 32 ) * DD);
        *(uint4*)&QP[rs + 64 ][cs] = *(const uint4*)(qsrc + (size_t)(rs + 64 ) * DD);
        *(uint4*)&QP[rs + 96 ][cs] = *(const uint4*)(qsrc + (size_t)(rs + 96 ) * DD);
    }

    uint4 pk0, pk1, pv0, pv1;
#define ATTN_LD(s0) \
    pk0 = *(const uint4*)(Kg  + (size_t)(b * SS + (s0) + rs) * DD + h * DHH + cs); \
    pk1 = *(const uint4*)(Kg  + (size_t)(b * SS + (s0) + rs + 32) * DD + h * DHH + cs); \
    pv0 = *(const uint4*)(Vtg + ((size_t)((b * HH + h) * DHH + rs)) * SS + (s0) + cs); \
    pv1 = *(const uint4*)(Vtg + ((size_t)((b * HH + h) * DHH + rs + 32)) * SS + (s0) + cs);

    ATTN_LD(0)
    // publish tile 0
    *(uint4*)&Ks [rs     ][cs] = pk0;
    *(uint4*)&Ks [rs + 32][cs] = pk1;
    *(uint4*)&Vts[rs     ][cs] = pv0;
    *(uint4*)&Vts[rs + 32][cs] = pv1;
    __syncthreads();                   // Q + tile0 visible

    // hoist Q fragments (Qs region dead afterwards -> reused as P)
    bf16x8 qa[2][2];
#pragma unroll
    for (int mt = 0; mt < 2; ++mt)
#pragma unroll
        for (int ki = 0; ki < 2; ++ki)
            qa[mt][ki] = ldfrag(&QP[w * 32 + mt * 16 + li][ki * 32 + q * 8]);

    FragU ones;
#pragma unroll
    for (int j = 0; j < 8; ++j) ones.s[j] = 0x3F80;  // bf16 1.0

    f32x4 o[2][4], lacc[2];
#pragma unroll
    for (int mt = 0; mt < 2; ++mt) {
        lacc[mt] = (f32x4)0.f;
#pragma unroll
        for (int nt = 0; nt < 4; ++nt) o[mt][nt] = (f32x4)0.f;
    }

    for (int kt = 0; kt < SS / 64; ++kt) {
        if (kt + 1 < SS / 64) { ATTN_LD((kt + 1) * 64) }  // overlap compute

        // S = (Q/8) K^T : 32 q-rows x 64 k-cols per wave
        f32x4 sc[2][4];
#pragma unroll
        for (int mt = 0; mt < 2; ++mt)
#pragma unroll
            for (int nt = 0; nt < 4; ++nt) sc[mt][nt] = (f32x4)0.f;
#pragma unroll
        for (int ki = 0; ki < 2; ++ki) {
            bf16x8 bb[4];
#pragma unroll
            for (int nt = 0; nt < 4; ++nt)
                bb[nt] = ldfrag(&Ks[nt * 16 + li][ki * 32 + q * 8]);
#pragma unroll
            for (int mt = 0; mt < 2; ++mt)
#pragma unroll
                for (int nt = 0; nt < 4; ++nt)
                    sc[mt][nt] = __builtin_amdgcn_mfma_f32_16x16x32_bf16(
                        qa[mt][ki], bb[nt], sc[mt][nt], 0, 0, 0);
        }

        // P = exp(S) -> bf16 LDS (wave-private rows of QP)
#pragma unroll
        for (int mt = 0; mt < 2; ++mt)
#pragma unroll
            for (int nt = 0; nt < 4; ++nt)
#pragma unroll
                for (int reg = 0; reg < 4; ++reg)
                    QP[w * 32 + mt * 16 + q * 4 + reg][nt * 16 + li] =
                        f2bu(__expf(sc[mt][nt][reg]));

        // O += P V ; l += P * 1  (V fragments reused across both mt)
#pragma unroll
        for (int ki = 0; ki < 2; ++ki) {
            bf16x8 vb[4];
#pragma unroll
            for (int nt = 0; nt < 4; ++nt)
                vb[nt] = ldfrag(&Vts[nt * 16 + li][ki * 32 + q * 8]);
#pragma unroll
            for (int mt = 0; mt < 2; ++mt) {
                const bf16x8 Pa = ldfrag(&QP[w * 32 + mt * 16 + li][ki * 32 + q * 8]);
#pragma unroll
                for (int nt = 0; nt < 4; ++nt)
                    o[mt][nt] = __builtin_amdgcn_mfma_f32_16x16x32_bf16(
                        Pa, vb[nt], o[mt][nt], 0, 0, 0);
                lacc[mt] = __builtin_amdgcn_mfma_f32_16x16x32_bf16(
                    Pa, ones.v, lacc[mt], 0, 0, 0);
            }
        }
        __syncthreads();                 // all reads of tile kt done
        if (kt + 1 < SS / 64) {
            *(uint4*)&Ks [rs     ][cs] = pk0;
            *(uint4*)&Ks [rs + 32][cs] = pk1;
            *(uint4*)&Vts[rs     ][cs] = pv0;
            *(uint4*)&Vts[rs + 32][cs] = pv1;
        }
        __syncthreads();                 // next tile visible
    }
#undef ATTN_LD

    // epilogue: 1/l, residual, fp32 store
#pragma unroll
    for (int mt = 0; mt < 2; ++mt) {
        float inv[4];
#pragma unroll
        for (int reg = 0; reg < 4; ++reg) inv[reg] = 1.f / lacc[mt][reg];
#pragma unroll
        for (int nt = 0; nt < 4; ++nt)
#pragma unroll
            for (int reg = 0; reg < 4; ++reg) {
                const size_t g = (size_t)(b * SS + qt * 128 + w * 32 + mt * 16 + q * 4 + reg) * DD
                               + h * DHH + nt * 16 + li;
                outp[g] = o[mt][nt][reg] * inv[reg] + queries[g];
            }
    }
}

// ---------------------------------------------------------------------------
extern "C" void kernel_launch(void* const* d_in, const int* in_sizes, int n_in,
                              void* d_out, int out_size, void* d_ws, size_t ws_size,
                              hipStream_t stream) {
    const float* queries = (const float*)d_in[0];
    const float* keys    = (const float*)d_in[1];
    const float* values  = (const float*)d_in[2];
    const float* Wq      = (const float*)d_in[3];
    const float* bq      = (const float*)d_in[4];
    const float* Wk      = (const float*)d_in[5];
    const float* bk      = (const float*)d_in[6];
    const float* Wv      = (const float*)d_in[7];
    const float* bv      = (const float*)d_in[8];
    float* outp = (float*)d_out;

    // scratch: prefer d_ws (54 MB needed); fall back to device globals.
    const size_t need = (6 * N_QKV + 3 * N_W) * sizeof(unsigned short);
    unsigned short *Xp, *Qp, *Kp, *Vtp, *Wtp;
    if (ws_size >= need) {
        Xp  = (unsigned short*)d_ws;
        Qp  = Xp + 3 * N_QKV;
        Kp  = Qp + N_QKV;
        Vtp = Kp + N_QKV;
        Wtp = Vtp + N_QKV;
    } else {
        hipGetSymbolAddress((void**)&Xp,  HIP_SYMBOL(g_X));
        hipGetSymbolAddress((void**)&Qp,  HIP_SYMBOL(g_Q));
        hipGetSymbolAddress((void**)&Kp,  HIP_SYMBOL(g_K));
        hipGetSymbolAddress((void**)&Vtp, HIP_SYMBOL(g_Vt));
        hipGetSymbolAddress((void**)&Wtp, HIP_SYMBOL(g_Wt));
    }

    const dim3 bp(256);
    cvt3<<<dim3(MM * DD / 1024, 3), bp, 0, stream>>>(queries, keys, values, Xp);
    transpose_w3<<<dim3(16, 16, 3), bp, 0, stream>>>(Wq, Wk, Wv, Wtp);
    proj3<<<dim3(8, 32, 3), bp, 0, stream>>>(Xp, Wtp, bq, bk, bv, Qp, Kp, Vtp);
    attn4<<<dim3(SS / 128, HH, BB), bp, 0, stream>>>(Qp, Kp, Vtp, queries, outp);
}